// Round 1
// baseline (210.996 us; speedup 1.0000x reference)
//
#include <hip/hip_runtime.h>
#include <hip/hip_bf16.h>

#define SEQ  8192
#define DIN  768
#define DOUT 64

typedef __attribute__((ext_vector_type(8))) short short8;
typedef __attribute__((ext_vector_type(4))) float f32x4;

__device__ inline unsigned short f2bf(float f) {
    __hip_bfloat16 h = __float2bfloat16(f);
    return __builtin_bit_cast(unsigned short, h);
}

// ---------------------------------------------------------------------------
// Kernel 1: fold Wq/Wk/Wv (fp32 [768][64]) into Wt bf16 [192][768] (transposed),
// with 1/sqrt(64) folded into the Wq block.
// ---------------------------------------------------------------------------
__global__ __launch_bounds__(256) void wconv_kernel(
    const float* __restrict__ Wq, const float* __restrict__ Wk,
    const float* __restrict__ Wv, unsigned short* __restrict__ Wt) {
    int idx = blockIdx.x * 256 + threadIdx.x;   // 0 .. 192*768-1
    int c = idx / DIN;                          // 0..191 output channel
    int k = idx - c * DIN;                      // 0..767
    int sel = c >> 6, cc = c & 63;
    const float* W = (sel == 0) ? Wq : ((sel == 1) ? Wk : Wv);
    float v = W[k * DOUT + cc];
    if (sel == 0) v *= 0.125f;                  // 1/sqrt(d_k)
    Wt[c * DIN + k] = f2bf(v);
}

// ---------------------------------------------------------------------------
// Kernel 2: projection GEMM. 256 blocks x 128 threads (2 waves), 32 rows/block.
// Q8 = (x@Wq)/8 bf16 [8192][64]; Kb = x@Wk bf16 [8192][64]; Vt = (x@Wv)^T bf16 [64][8192].
// ---------------------------------------------------------------------------
__global__ __launch_bounds__(128) void proj_kernel(
    const float* __restrict__ x, const unsigned short* __restrict__ Wt,
    unsigned short* __restrict__ Q8, unsigned short* __restrict__ Kb,
    unsigned short* __restrict__ Vt) {
    __shared__ unsigned short xs[32 * 72];    // x tile  [32 rows][64 k] pitch 72
    __shared__ unsigned short ws[192 * 72];   // Wt tile [192 ch ][64 k] pitch 72

    const int tid  = threadIdx.x;
    const int m0   = blockIdx.x * 32;
    const int lane = tid & 63;
    const int wv   = tid >> 6;          // wave 0/1
    const int g    = lane >> 4;         // 4 k-groups
    const int l15  = lane & 15;

    f32x4 zero = {0.f, 0.f, 0.f, 0.f};
    f32x4 acc[12];
#pragma unroll
    for (int i = 0; i < 12; ++i) acc[i] = zero;

    for (int kt = 0; kt < 12; ++kt) {
        const int k0 = kt * 64;
        // ---- stage x tile (fp32 -> bf16) ----
        {
            int r = tid >> 2, c4 = (tid & 3) * 16;
            const float4* src4 = reinterpret_cast<const float4*>(
                x + (m0 + r) * DIN + k0 + c4);
            float4 f0 = src4[0], f1 = src4[1], f2 = src4[2], f3 = src4[3];
            short8 lo, hi;
            lo[0]=(short)f2bf(f0.x); lo[1]=(short)f2bf(f0.y); lo[2]=(short)f2bf(f0.z); lo[3]=(short)f2bf(f0.w);
            lo[4]=(short)f2bf(f1.x); lo[5]=(short)f2bf(f1.y); lo[6]=(short)f2bf(f1.z); lo[7]=(short)f2bf(f1.w);
            hi[0]=(short)f2bf(f2.x); hi[1]=(short)f2bf(f2.y); hi[2]=(short)f2bf(f2.z); hi[3]=(short)f2bf(f2.w);
            hi[4]=(short)f2bf(f3.x); hi[5]=(short)f2bf(f3.y); hi[6]=(short)f2bf(f3.z); hi[7]=(short)f2bf(f3.w);
            *(short8*)&xs[r * 72 + c4]     = lo;
            *(short8*)&xs[r * 72 + c4 + 8] = hi;
        }
        // ---- stage Wt tile (bf16 copy) ----
#pragma unroll
        for (int p = 0; p < 12; ++p) {
            int c    = p * 16 + (tid >> 3);
            int col8 = (tid & 7) * 8;
            *(short8*)&ws[c * 72 + col8] =
                *(const short8*)&Wt[c * DIN + k0 + col8];
        }
        __syncthreads();
        // ---- MFMA compute ----
        short8 a0 = *(short8*)&xs[(wv * 16 + l15) * 72 + g * 8];
        short8 a1 = *(short8*)&xs[(wv * 16 + l15) * 72 + g * 8 + 32];
#pragma unroll
        for (int nt = 0; nt < 12; ++nt) {
            short8 b0 = *(short8*)&ws[(nt * 16 + l15) * 72 + g * 8];
            short8 b1 = *(short8*)&ws[(nt * 16 + l15) * 72 + g * 8 + 32];
            acc[nt] = __builtin_amdgcn_mfma_f32_16x16x32_bf16(a0, b0, acc[nt], 0, 0, 0);
            acc[nt] = __builtin_amdgcn_mfma_f32_16x16x32_bf16(a1, b1, acc[nt], 0, 0, 0);
        }
        __syncthreads();
    }
    // ---- epilogue: scatter to Q8 / Kb / Vt ----
#pragma unroll
    for (int nt = 0; nt < 12; ++nt) {
#pragma unroll
        for (int r = 0; r < 4; ++r) {
            int row = m0 + wv * 16 + g * 4 + r;
            int col = nt * 16 + l15;
            unsigned short b = f2bf(acc[nt][r]);
            if (col < 64)        Q8[row * 64 + col]        = b;
            else if (col < 128)  Kb[row * 64 + (col - 64)] = b;
            else                 Vt[(size_t)(col - 128) * SEQ + row] = b;
        }
    }
}

// ---------------------------------------------------------------------------
// Kernel 3: flash attention. 256 blocks x 128 threads (2 waves), 16 q-rows/wave,
// KV tiles of 64, double-buffered LDS staging (pitch 72 = +8 pad).
// ---------------------------------------------------------------------------
__global__ __launch_bounds__(128) void flash_kernel(
    const unsigned short* __restrict__ Q8, const unsigned short* __restrict__ Kb,
    const unsigned short* __restrict__ Vt, float* __restrict__ Out) {
    __shared__ unsigned short kt[2][64 * 72];   // K tile  [kv row][d]  pitch 72
    __shared__ unsigned short vt[2][64 * 72];   // V tile  [d][kv row]  pitch 72
    __shared__ unsigned short pb[2][16 * 72];   // per-wave P buffer [qrow][kv] pitch 72

    const int tid  = threadIdx.x;
    const int wv   = tid >> 6;
    const int lane = tid & 63;
    const int g    = lane >> 4;
    const int l15  = lane & 15;
    const int q0   = blockIdx.x * 32 + wv * 16;

    // Q fragments (held in registers for the whole kernel); Q already scaled by 1/8
    short8 qa0 = *(const short8*)&Q8[(q0 + l15) * 64 + g * 8];
    short8 qa1 = *(const short8*)&Q8[(q0 + l15) * 64 + g * 8 + 32];

    f32x4 zero = {0.f, 0.f, 0.f, 0.f};
    f32x4 o[4] = {zero, zero, zero, zero};
    float m[4]  = {-1e30f, -1e30f, -1e30f, -1e30f};
    float ln[4] = {0.f, 0.f, 0.f, 0.f};

    short8 sk[4], sv[4];   // staging registers
    const int sr = tid >> 3;         // 0..15
    const int sc = (tid & 7) * 8;    // 0..56

    auto stage_load = [&](int t) {
        const int kv = t * 64;
#pragma unroll
        for (int p = 0; p < 4; ++p) {
            sk[p] = *(const short8*)&Kb[(kv + p * 16 + sr) * 64 + sc];
            sv[p] = *(const short8*)&Vt[(size_t)(p * 16 + sr) * SEQ + kv + sc];
        }
    };
    auto stage_commit = [&](int buf) {
#pragma unroll
        for (int p = 0; p < 4; ++p) {
            *(short8*)&kt[buf][(p * 16 + sr) * 72 + sc] = sk[p];
            *(short8*)&vt[buf][(p * 16 + sr) * 72 + sc] = sv[p];
        }
    };

    stage_load(0);
    stage_commit(0);
    __syncthreads();

    for (int t = 0; t < SEQ / 64; ++t) {
        const int cur = t & 1;
        if (t + 1 < SEQ / 64) stage_load(t + 1);   // issue next-tile loads early

        // ---- S = Q @ K^T (pre-scaled) ----
        f32x4 s[4];
#pragma unroll
        for (int nt = 0; nt < 4; ++nt) {
            s[nt] = zero;
            short8 b0 = *(short8*)&kt[cur][(nt * 16 + l15) * 72 + g * 8];
            short8 b1 = *(short8*)&kt[cur][(nt * 16 + l15) * 72 + g * 8 + 32];
            s[nt] = __builtin_amdgcn_mfma_f32_16x16x32_bf16(qa0, b0, s[nt], 0, 0, 0);
            s[nt] = __builtin_amdgcn_mfma_f32_16x16x32_bf16(qa1, b1, s[nt], 0, 0, 0);
        }

        // ---- online softmax (rows live in 16-lane groups) ----
        float al[4];
#pragma unroll
        for (int r = 0; r < 4; ++r) {
            float v = fmaxf(fmaxf(s[0][r], s[1][r]), fmaxf(s[2][r], s[3][r]));
            v = fmaxf(v, __shfl_xor(v, 1));
            v = fmaxf(v, __shfl_xor(v, 2));
            v = fmaxf(v, __shfl_xor(v, 4));
            v = fmaxf(v, __shfl_xor(v, 8));
            float mn = fmaxf(m[r], v);
            al[r] = __expf(m[r] - mn);
            m[r]  = mn;
        }
        float psum[4] = {0.f, 0.f, 0.f, 0.f};
#pragma unroll
        for (int nt = 0; nt < 4; ++nt) {
#pragma unroll
            for (int r = 0; r < 4; ++r) {
                float p = __expf(s[nt][r] - m[r]);
                psum[r] += p;
                pb[wv][(g * 4 + r) * 72 + nt * 16 + l15] = f2bf(p);
            }
        }
#pragma unroll
        for (int r = 0; r < 4; ++r) {
            float v = psum[r];
            v += __shfl_xor(v, 1);
            v += __shfl_xor(v, 2);
            v += __shfl_xor(v, 4);
            v += __shfl_xor(v, 8);
            ln[r] = ln[r] * al[r] + v;
#pragma unroll
            for (int dn = 0; dn < 4; ++dn) o[dn][r] *= al[r];
        }
        asm volatile("s_waitcnt lgkmcnt(0)" ::: "memory");  // P writes visible to wave

        // ---- O += P @ V ----
        short8 pa0 = *(short8*)&pb[wv][l15 * 72 + g * 8];
        short8 pa1 = *(short8*)&pb[wv][l15 * 72 + g * 8 + 32];
#pragma unroll
        for (int dn = 0; dn < 4; ++dn) {
            short8 b0 = *(short8*)&vt[cur][(dn * 16 + l15) * 72 + g * 8];
            short8 b1 = *(short8*)&vt[cur][(dn * 16 + l15) * 72 + g * 8 + 32];
            o[dn] = __builtin_amdgcn_mfma_f32_16x16x32_bf16(pa0, b0, o[dn], 0, 0, 0);
            o[dn] = __builtin_amdgcn_mfma_f32_16x16x32_bf16(pa1, b1, o[dn], 0, 0, 0);
        }

        if (t + 1 < SEQ / 64) stage_commit((t + 1) & 1);
        __syncthreads();
    }

    // ---- epilogue: O / l ----
#pragma unroll
    for (int dn = 0; dn < 4; ++dn)
#pragma unroll
        for (int r = 0; r < 4; ++r)
            Out[(q0 + g * 4 + r) * 64 + dn * 16 + l15] = o[dn][r] / ln[r];
}

// ---------------------------------------------------------------------------
extern "C" void kernel_launch(void* const* d_in, const int* in_sizes, int n_in,
                              void* d_out, int out_size, void* d_ws, size_t ws_size,
                              hipStream_t stream) {
    const float* x  = (const float*)d_in[0];
    const float* Wq = (const float*)d_in[1];
    const float* Wk = (const float*)d_in[2];
    const float* Wv = (const float*)d_in[3];
    float* out = (float*)d_out;

    char* ws = (char*)d_ws;
    unsigned short* Wt = (unsigned short*)(ws);                       // 192*768*2   = 294912 B
    unsigned short* Q8 = (unsigned short*)(ws + 294912);              // 8192*64*2   = 1 MiB
    unsigned short* Kb = (unsigned short*)(ws + 294912 + 1048576);    // 1 MiB
    unsigned short* Vt = (unsigned short*)(ws + 294912 + 2097152);    // 1 MiB

    wconv_kernel<<<dim3(576), dim3(256), 0, stream>>>(Wq, Wk, Wv, Wt);
    proj_kernel<<<dim3(256), dim3(128), 0, stream>>>(x, Wt, Q8, Kb, Vt);
    flash_kernel<<<dim3(256), dim3(128), 0, stream>>>(Q8, Kb, Vt, out);
}

// Round 3
// 122.857 us; speedup vs baseline: 1.7174x; 1.7174x over previous
//
#include <hip/hip_runtime.h>
#include <hip/hip_bf16.h>

#define SEQ  8192
#define DIN  768
#define DOUT 64

typedef __attribute__((ext_vector_type(8))) short short8;
typedef __attribute__((ext_vector_type(4))) short s16x4;
typedef __attribute__((ext_vector_type(4))) float f32x4;

__device__ inline unsigned short f2bf(float f) {
    __hip_bfloat16 h = __float2bfloat16(f);
    return __builtin_bit_cast(unsigned short, h);
}

// ---------------------------------------------------------------------------
// Kernel 1: fold Wq/Wk/Wv (fp32 [768][64]) into Wt bf16 [192][768] (transposed),
// with 1/sqrt(64) folded into the Wq block.
// ---------------------------------------------------------------------------
__global__ __launch_bounds__(256) void wconv_kernel(
    const float* __restrict__ Wq, const float* __restrict__ Wk,
    const float* __restrict__ Wv, unsigned short* __restrict__ Wt) {
    int idx = blockIdx.x * 256 + threadIdx.x;   // 0 .. 192*768-1
    int c = idx / DIN;                          // 0..191 output channel
    int k = idx - c * DIN;                      // 0..767
    int sel = c >> 6, cc = c & 63;
    const float* W = (sel == 0) ? Wq : ((sel == 1) ? Wk : Wv);
    float v = W[k * DOUT + cc];
    if (sel == 0) v *= 0.125f;                  // 1/sqrt(d_k)
    Wt[c * DIN + k] = f2bf(v);
}

// ---------------------------------------------------------------------------
// Kernel 2: projection GEMM. 512 blocks x 256 threads (4 waves), 16 rows/block;
// wave w computes output channels [w*48, w*48+48).  8 waves/CU.
// Q8 = (x@Wq)/8 bf16 [8192][64]; Kb = x@Wk bf16 [8192][64]; Vt = (x@Wv)^T bf16 [64][8192].
// ---------------------------------------------------------------------------
__global__ __launch_bounds__(256) void proj_kernel(
    const float* __restrict__ x, const unsigned short* __restrict__ Wt,
    unsigned short* __restrict__ Q8, unsigned short* __restrict__ Kb,
    unsigned short* __restrict__ Vt) {
    __shared__ unsigned short xs[16 * 72];    // x tile  [16 rows][64 k] pitch 72
    __shared__ unsigned short ws[192 * 72];   // Wt tile [192 ch ][64 k] pitch 72

    const int tid  = threadIdx.x;
    const int m0   = blockIdx.x * 16;
    const int lane = tid & 63;
    const int w    = tid >> 6;          // wave 0..3
    const int g    = lane >> 4;
    const int l15  = lane & 15;

    f32x4 zero = {0.f, 0.f, 0.f, 0.f};
    f32x4 acc[3] = {zero, zero, zero};

    for (int kt = 0; kt < 12; ++kt) {
        const int k0 = kt * 64;
        // ---- stage x tile (fp32 -> bf16): 16x64 elems, 1 float4 per thread ----
        {
            int r = tid >> 4, c4 = (tid & 15) * 4;
            float4 f = *reinterpret_cast<const float4*>(&x[(m0 + r) * DIN + k0 + c4]);
            s16x4 o4;
            o4[0] = (short)f2bf(f.x); o4[1] = (short)f2bf(f.y);
            o4[2] = (short)f2bf(f.z); o4[3] = (short)f2bf(f.w);
            *(s16x4*)&xs[r * 72 + c4] = o4;
        }
        // ---- stage Wt tile: 192x64, 6 short8 per thread ----
#pragma unroll
        for (int p = 0; p < 6; ++p) {
            int c    = p * 32 + (tid >> 3);
            int col8 = (tid & 7) * 8;
            *(short8*)&ws[c * 72 + col8] =
                *(const short8*)&Wt[c * DIN + k0 + col8];
        }
        __syncthreads();
        // ---- MFMA: each wave does its 3 channel-tiles ----
        short8 a0 = *(short8*)&xs[l15 * 72 + g * 8];
        short8 a1 = *(short8*)&xs[l15 * 72 + g * 8 + 32];
#pragma unroll
        for (int i = 0; i < 3; ++i) {
            int nt = w * 3 + i;
            short8 b0 = *(short8*)&ws[(nt * 16 + l15) * 72 + g * 8];
            short8 b1 = *(short8*)&ws[(nt * 16 + l15) * 72 + g * 8 + 32];
            acc[i] = __builtin_amdgcn_mfma_f32_16x16x32_bf16(a0, b0, acc[i], 0, 0, 0);
            acc[i] = __builtin_amdgcn_mfma_f32_16x16x32_bf16(a1, b1, acc[i], 0, 0, 0);
        }
        __syncthreads();
    }
    // ---- epilogue: scatter to Q8 / Kb / Vt ----
#pragma unroll
    for (int i = 0; i < 3; ++i) {
#pragma unroll
        for (int r = 0; r < 4; ++r) {
            int row = m0 + g * 4 + r;
            int col = (w * 3 + i) * 16 + l15;
            unsigned short b = f2bf(acc[i][r]);
            if (col < 64)        Q8[row * 64 + col]        = b;
            else if (col < 128)  Kb[row * 64 + (col - 64)] = b;
            else                 Vt[(size_t)(col - 128) * SEQ + row] = b;
        }
    }
}

// ---------------------------------------------------------------------------
// Kernel 3: flash attention with KV-split. Grid (256 q-tiles, NS splits),
// 64 threads = 1 independent wave per block; 32 q-rows/wave; K/V fragments
// loaded DIRECT from global (L2-resident, coalesced) -- no K/V LDS, no barriers.
// Writes unnormalized O + (m, l) partials per split.
// ---------------------------------------------------------------------------
__global__ __launch_bounds__(64) void flash_kernel(
    const unsigned short* __restrict__ Q8, const unsigned short* __restrict__ Kb,
    const unsigned short* __restrict__ Vt, float* __restrict__ Op,
    float* __restrict__ Mp, float* __restrict__ Lp, int ntiles) {
    __shared__ unsigned short pb[32 * 72];   // P buffer [32 qrow][64 kv] pitch 72

    const int lane = threadIdx.x;
    const int g    = lane >> 4;
    const int l15  = lane & 15;
    const int q0   = blockIdx.x * 32;
    const int kv0  = blockIdx.y * (ntiles * 64);

    // Q fragments (2 row-groups x 2 k-halves), Q pre-scaled by 1/8
    short8 qa[4];
#pragma unroll
    for (int qg = 0; qg < 2; ++qg) {
        qa[qg * 2 + 0] = *(const short8*)&Q8[(q0 + qg * 16 + l15) * 64 + g * 8];
        qa[qg * 2 + 1] = *(const short8*)&Q8[(q0 + qg * 16 + l15) * 64 + g * 8 + 32];
    }

    f32x4 zero = {0.f, 0.f, 0.f, 0.f};
    f32x4 o[2][4];
    float m[2][4], ln[2][4];
#pragma unroll
    for (int qg = 0; qg < 2; ++qg)
#pragma unroll
        for (int i = 0; i < 4; ++i) {
            o[qg][i] = zero; m[qg][i] = -1e30f; ln[qg][i] = 0.f;
        }

    for (int t = 0; t < ntiles; ++t) {
        const int kvb = kv0 + t * 64;

        // ---- S = Q @ K^T : K fragments direct from global ----
        f32x4 s[2][4];
#pragma unroll
        for (int qg = 0; qg < 2; ++qg)
#pragma unroll
            for (int nt = 0; nt < 4; ++nt) s[qg][nt] = zero;
#pragma unroll
        for (int nt = 0; nt < 4; ++nt) {
            const unsigned short* kp = &Kb[(kvb + nt * 16 + l15) * 64 + g * 8];
            short8 b0 = *(const short8*)kp;
            short8 b1 = *(const short8*)(kp + 32);
            s[0][nt] = __builtin_amdgcn_mfma_f32_16x16x32_bf16(qa[0], b0, s[0][nt], 0, 0, 0);
            s[0][nt] = __builtin_amdgcn_mfma_f32_16x16x32_bf16(qa[1], b1, s[0][nt], 0, 0, 0);
            s[1][nt] = __builtin_amdgcn_mfma_f32_16x16x32_bf16(qa[2], b0, s[1][nt], 0, 0, 0);
            s[1][nt] = __builtin_amdgcn_mfma_f32_16x16x32_bf16(qa[3], b1, s[1][nt], 0, 0, 0);
        }

        // ---- online softmax (row r of group qg lives at lane-group g, reg r) ----
#pragma unroll
        for (int qg = 0; qg < 2; ++qg) {
#pragma unroll
            for (int r = 0; r < 4; ++r) {
                float v = fmaxf(fmaxf(s[qg][0][r], s[qg][1][r]),
                                fmaxf(s[qg][2][r], s[qg][3][r]));
                v = fmaxf(v, __shfl_xor(v, 1));
                v = fmaxf(v, __shfl_xor(v, 2));
                v = fmaxf(v, __shfl_xor(v, 4));
                v = fmaxf(v, __shfl_xor(v, 8));
                float mn = fmaxf(m[qg][r], v);
                float a  = __expf(m[qg][r] - mn);
                m[qg][r] = mn;
                ln[qg][r] *= a;
#pragma unroll
                for (int dn = 0; dn < 4; ++dn) o[qg][dn][r] *= a;
                float ps = 0.f;
#pragma unroll
                for (int nt = 0; nt < 4; ++nt) {
                    float p = __expf(s[qg][nt][r] - mn);
                    ps += p;
                    pb[(qg * 16 + g * 4 + r) * 72 + nt * 16 + l15] = f2bf(p);
                }
                ps += __shfl_xor(ps, 1);
                ps += __shfl_xor(ps, 2);
                ps += __shfl_xor(ps, 4);
                ps += __shfl_xor(ps, 8);
                ln[qg][r] += ps;
            }
        }
        asm volatile("s_waitcnt lgkmcnt(0)" ::: "memory");
        __builtin_amdgcn_sched_barrier(0);

        // ---- O += P @ V : V fragments direct from global (Vt transposed) ----
        short8 pa[4];
#pragma unroll
        for (int qg = 0; qg < 2; ++qg) {
            pa[qg * 2 + 0] = *(short8*)&pb[(qg * 16 + l15) * 72 + g * 8];
            pa[qg * 2 + 1] = *(short8*)&pb[(qg * 16 + l15) * 72 + g * 8 + 32];
        }
#pragma unroll
        for (int dn = 0; dn < 4; ++dn) {
            const unsigned short* vp = &Vt[(size_t)(dn * 16 + l15) * SEQ + kvb + g * 8];
            short8 vb0 = *(const short8*)vp;
            short8 vb1 = *(const short8*)(vp + 32);
            o[0][dn] = __builtin_amdgcn_mfma_f32_16x16x32_bf16(pa[0], vb0, o[0][dn], 0, 0, 0);
            o[0][dn] = __builtin_amdgcn_mfma_f32_16x16x32_bf16(pa[1], vb1, o[0][dn], 0, 0, 0);
            o[1][dn] = __builtin_amdgcn_mfma_f32_16x16x32_bf16(pa[2], vb0, o[1][dn], 0, 0, 0);
            o[1][dn] = __builtin_amdgcn_mfma_f32_16x16x32_bf16(pa[3], vb1, o[1][dn], 0, 0, 0);
        }
    }

    // ---- epilogue: unnormalized partials ----
    const size_t sb = (size_t)blockIdx.y * SEQ;
#pragma unroll
    for (int qg = 0; qg < 2; ++qg) {
#pragma unroll
        for (int dn = 0; dn < 4; ++dn)
#pragma unroll
            for (int r = 0; r < 4; ++r)
                Op[(sb + q0 + qg * 16 + g * 4 + r) * 64 + dn * 16 + l15] = o[qg][dn][r];
        if (l15 == 0) {
#pragma unroll
            for (int r = 0; r < 4; ++r) {
                Mp[sb + q0 + qg * 16 + g * 4 + r] = m[qg][r];
                Lp[sb + q0 + qg * 16 + g * 4 + r] = ln[qg][r];
            }
        }
    }
}

// ---------------------------------------------------------------------------
// Kernel 4: combine split partials.  2048 blocks x 256 threads; 4 q-rows/block.
// ---------------------------------------------------------------------------
__global__ __launch_bounds__(256) void reduce_kernel(
    const float* __restrict__ Op, const float* __restrict__ Mp,
    const float* __restrict__ Lp, float* __restrict__ Out, int NS) {
    int q = blockIdx.x * 4 + (threadIdx.x >> 6);
    int d = threadIdx.x & 63;
    float M = -1e30f;
    for (int s = 0; s < NS; ++s) M = fmaxf(M, Mp[s * SEQ + q]);
    float L = 0.f, acc = 0.f;
    for (int s = 0; s < NS; ++s) {
        float w = __expf(Mp[s * SEQ + q] - M);
        L   += Lp[s * SEQ + q] * w;
        acc += Op[((size_t)s * SEQ + q) * 64 + d] * w;
    }
    Out[q * 64 + d] = acc / L;
}

// ---------------------------------------------------------------------------
extern "C" void kernel_launch(void* const* d_in, const int* in_sizes, int n_in,
                              void* d_out, int out_size, void* d_ws, size_t ws_size,
                              hipStream_t stream) {
    const float* x  = (const float*)d_in[0];
    const float* Wq = (const float*)d_in[1];
    const float* Wk = (const float*)d_in[2];
    const float* Wv = (const float*)d_in[3];
    float* out = (float*)d_out;

    char* ws = (char*)d_ws;
    unsigned short* Wt = (unsigned short*)(ws);                       // 294912 B
    unsigned short* Q8 = (unsigned short*)(ws + 294912);              // 1 MiB
    unsigned short* Kb = (unsigned short*)(ws + 294912 + 1048576);    // 1 MiB
    unsigned short* Vt = (unsigned short*)(ws + 294912 + 2097152);    // 1 MiB
    const size_t fixed = 294912 + 3 * 1048576;                        // 3440640

    // pick largest split count that fits the workspace
    int NS = 16;
    while (NS > 1 && fixed + (size_t)NS * (2097152 + 65536) > ws_size) NS >>= 1;
    float* Op = (float*)(ws + fixed);                                  // NS*2 MiB
    float* Mp = (float*)(ws + fixed + (size_t)NS * 2097152);           // NS*32 KiB
    float* Lp = (float*)(ws + fixed + (size_t)NS * 2097152 + (size_t)NS * 32768);
    const int ntiles = SEQ / (NS * 64);

    wconv_kernel<<<dim3(576), dim3(256), 0, stream>>>(Wq, Wk, Wv, Wt);
    proj_kernel<<<dim3(512), dim3(256), 0, stream>>>(x, Wt, Q8, Kb, Vt);
    flash_kernel<<<dim3(256, NS), dim3(64), 0, stream>>>(Q8, Kb, Vt, Op, Mp, Lp, ntiles);
    reduce_kernel<<<dim3(2048), dim3(256), 0, stream>>>(Op, Mp, Lp, out, NS);
}